// Round 17
// baseline (175.870 us; speedup 1.0000x reference)
//
#include <hip/hip_runtime.h>
#include <hip/hip_bf16.h>

// chem_transformer2D — round 17: FC+ReLU+BN fused into the attn epilogue.
// Each 8-wave attn block already holds 128 complete ap rows in Osw in
// MFMA-A-fragment order -> the final GEMM (M=16/wave, N=256, K=256) runs
// in-kernel: gemm_bn2 dispatch and the ap global round-trip are deleted.
// attn main loop = round-16 verbatim (8-wave, KB=64, counted vmcnt).
// mlp3_plus / pack_wt = round 15/16 verbatim.

typedef __attribute__((ext_vector_type(8))) short bf16x8;
typedef __attribute__((ext_vector_type(4))) float f32x4;
typedef unsigned short u16;

__device__ __forceinline__ unsigned int f2bfbits(float f) {
  union { float f; unsigned int i; } v; v.f = f;
  return (v.i + 0x7fffu + ((v.i >> 16) & 1u)) >> 16;  // RNE, finite inputs
}
__device__ __forceinline__ unsigned int pk2(float a, float b) {
  return f2bfbits(a) | (f2bfbits(b) << 16);
}
__device__ __forceinline__ float bf2f(u16 x) {
  union { unsigned int i; float f; } v;
  v.i = (unsigned int)x << 16;
  return v.f;
}

// ---------------- weight pack: W[256][256] f32 -> Wt[256][256] bf16 (Wt[n][k]=W[k][n]) ----
__global__ void pack_wt(const float* __restrict__ w0, const float* __restrict__ w1,
                        const float* __restrict__ w2, const float* __restrict__ w3,
                        const float* __restrict__ w4, const float* __restrict__ w5,
                        const float* __restrict__ w6, const float* __restrict__ w7,
                        u16* __restrict__ out) {
  const float* wsel[8] = {w0, w1, w2, w3, w4, w5, w6, w7};
  const float* W = wsel[blockIdx.y];
  u16* o = out + (size_t)blockIdx.y * 65536;
  int i0 = blockIdx.x * 1024 + threadIdx.x * 4;  // grid.x=64, block=256
  int n = i0 >> 8, k = i0 & 255;
  float a = W[(k + 0) * 256 + n];
  float b = W[(k + 1) * 256 + n];
  float c = W[(k + 2) * 256 + n];
  float d = W[(k + 3) * 256 + n];
  uint2 pv;
  pv.x = pk2(a, b);
  pv.y = pk2(c, d);
  *(uint2*)(o + i0) = pv;
}

// ---------------- merged: 3-MLP stack (blocks 0..511) + disto transpose (512..4607) ----
__global__ __launch_bounds__(256, 2)
void mlp3_plus(const float* __restrict__ seqA, const float* __restrict__ seqB,
               const u16* __restrict__ Wt8,
               const float* __restrict__ kb1, const float* __restrict__ kb2,
               const float* __restrict__ qb1, const float* __restrict__ qb2,
               const float* __restrict__ vb1, const float* __restrict__ vb2,
               u16* __restrict__ kA, u16* __restrict__ qA, u16* __restrict__ vA,
               u16* __restrict__ kB, u16* __restrict__ qB, u16* __restrict__ vB,
               const float* __restrict__ D, u16* __restrict__ Dt)
{
  __shared__ union {
    struct {
      u16 As[64][256];  // 32KB, chunk-swizzle ch^(row&7)
      u16 Hl[64][256];  // 32KB, same swizzle
    } m;
    u16 T[64][72];      // disto-transpose tile (+8 pad)
  } sh;

  const int tid = threadIdx.x;

  if (blockIdx.x >= 512) {
    // pack_disto path: Dt[b][m][l] = bf16(D[b][l][m])
    const int pb = blockIdx.x - 512;          // 0..4095
    const int m0 = (pb & 15) * 64;
    const int l0 = ((pb >> 4) & 15) * 64;
    const int b = pb >> 8;
    const float* src = D + (size_t)b * (1024 * 1024);
    u16* dst = Dt + (size_t)b * (1024 * 1024);
    const int r = tid >> 2, c0 = (tid & 3) * 16;
    float4 f[4];
#pragma unroll
    for (int q = 0; q < 4; ++q)
      f[q] = *(const float4*)(src + (size_t)(l0 + r) * 1024 + m0 + c0 + q * 4);
    uint4 p0, p1;
    p0.x = pk2(f[0].x, f[0].y); p0.y = pk2(f[0].z, f[0].w);
    p0.z = pk2(f[1].x, f[1].y); p0.w = pk2(f[1].z, f[1].w);
    p1.x = pk2(f[2].x, f[2].y); p1.y = pk2(f[2].z, f[2].w);
    p1.z = pk2(f[3].x, f[3].y); p1.w = pk2(f[3].z, f[3].w);
    *(uint4*)&sh.T[r][c0] = p0;
    *(uint4*)&sh.T[r][c0 + 8] = p1;
    __syncthreads();
    u16 vals[16];
#pragma unroll
    for (int k = 0; k < 16; ++k) vals[k] = sh.T[c0 + k][r];
    *(uint4*)(dst + (size_t)(m0 + r) * 1024 + l0 + c0) = *(uint4*)&vals[0];
    *(uint4*)(dst + (size_t)(m0 + r) * 1024 + l0 + c0 + 8) = *(uint4*)&vals[8];
    return;
  }

  // mlp3 path (depth-2 weight pipeline)
  const int lane = tid & 63;
  const int w = tid >> 6;
  const int l15 = lane & 15, lq = lane >> 4;
  const int seqsel = blockIdx.x >> 8;
  const size_t m0 = (size_t)(blockIdx.x & 255) * 64;
  const float* __restrict__ seq = seqsel ? seqB : seqA;

  {
    const int row = tid >> 2, cg = tid & 3;
    const float* src = seq + (m0 + row) * 256 + cg * 64;
#pragma unroll
    for (int cc = 0; cc < 8; ++cc) {
      float4 f0 = *(const float4*)(src + cc * 8);
      float4 f1 = *(const float4*)(src + cc * 8 + 4);
      uint4 pk;
      pk.x = pk2(f0.x, f0.y);
      pk.y = pk2(f0.z, f0.w);
      pk.z = pk2(f1.x, f1.y);
      pk.w = pk2(f1.z, f1.w);
      const int ch = (cg * 8 + cc) ^ (row & 7);
      *(uint4*)&sh.m.As[row][ch * 8] = pk;
    }
  }
  __syncthreads();

  for (int mlp = 0; mlp < 3; ++mlp) {
    const u16* __restrict__ W1 = Wt8 + (size_t)(mlp * 2) * 65536;
    const u16* __restrict__ W2 = W1 + 65536;
    const float* __restrict__ b1 = (mlp == 0) ? kb1 : (mlp == 1) ? qb1 : vb1;
    const float* __restrict__ b2 = (mlp == 0) ? kb2 : (mlp == 1) ? qb2 : vb2;
    u16* __restrict__ dst =
        (mlp == 0) ? (seqsel ? kB : kA) : (mlp == 1) ? (seqsel ? qB : qA) : (seqsel ? vB : vA);

    const u16* __restrict__ w1b = W1 + (size_t)(w * 64 + l15) * 256 + lq * 8;
    const u16* __restrict__ w2b = W2 + (size_t)(w * 64 + l15) * 256 + lq * 8;

    bf16x8 wf[3][4];
#pragma unroll
    for (int ni = 0; ni < 4; ++ni) wf[0][ni] = *(const bf16x8*)(w1b + ni * 4096);
#pragma unroll
    for (int ni = 0; ni < 4; ++ni) wf[1][ni] = *(const bf16x8*)(w1b + ni * 4096 + 32);

    float b1v[4][4];
#pragma unroll
    for (int ni = 0; ni < 4; ++ni)
#pragma unroll
      for (int r = 0; r < 4; ++r) b1v[ni][r] = b1[w * 64 + ni * 16 + 4 * lq + r];
    float b2v[4];
#pragma unroll
    for (int ni = 0; ni < 4; ++ni) b2v[ni] = b2[w * 64 + ni * 16 + l15];

    f32x4 a1[4][4];
#pragma unroll
    for (int ni = 0; ni < 4; ++ni)
#pragma unroll
      for (int mj = 0; mj < 4; ++mj) a1[ni][mj] = (f32x4)0.0f;
#pragma unroll
    for (int ks = 0; ks < 8; ++ks) {
      if (ks + 2 < 8) {
#pragma unroll
        for (int ni = 0; ni < 4; ++ni)
          wf[(ks + 2) % 3][ni] = *(const bf16x8*)(w1b + ni * 4096 + (ks + 2) * 32);
      }
      bf16x8 af[4];
#pragma unroll
      for (int mj = 0; mj < 4; ++mj) {
        const int row = mj * 16 + l15;
        const int ch = (ks * 4 + lq) ^ (row & 7);
        af[mj] = *(const bf16x8*)&sh.m.As[row][ch * 8];
      }
#pragma unroll
      for (int ni = 0; ni < 4; ++ni)
#pragma unroll
        for (int mj = 0; mj < 4; ++mj)
          a1[ni][mj] = __builtin_amdgcn_mfma_f32_16x16x32_bf16(
              wf[ks % 3][ni], af[mj], a1[ni][mj], 0, 0, 0);
    }

    __syncthreads();

#pragma unroll
    for (int ni = 0; ni < 4; ++ni) wf[0][ni] = *(const bf16x8*)(w2b + ni * 4096);
#pragma unroll
    for (int ni = 0; ni < 4; ++ni) wf[1][ni] = *(const bf16x8*)(w2b + ni * 4096 + 32);

#pragma unroll
    for (int ni = 0; ni < 4; ++ni) {
      const int chl = w * 8 + ni * 2 + (lq >> 1);
#pragma unroll
      for (int mj = 0; mj < 4; ++mj) {
        const int m = mj * 16 + l15;
        float h0 = fmaxf(a1[ni][mj][0] + b1v[ni][0], 0.f);
        float h1 = fmaxf(a1[ni][mj][1] + b1v[ni][1], 0.f);
        float h2 = fmaxf(a1[ni][mj][2] + b1v[ni][2], 0.f);
        float h3 = fmaxf(a1[ni][mj][3] + b1v[ni][3], 0.f);
        uint2 pv;
        pv.x = pk2(h0, h1);
        pv.y = pk2(h2, h3);
        const int ch = chl ^ (m & 7);
        *(uint2*)&sh.m.Hl[m][ch * 8 + (lq & 1) * 4] = pv;
      }
    }
    __syncthreads();

    f32x4 a2[4][4];
#pragma unroll
    for (int mi = 0; mi < 4; ++mi)
#pragma unroll
      for (int ni = 0; ni < 4; ++ni) a2[mi][ni] = (f32x4)0.0f;
#pragma unroll
    for (int ks = 0; ks < 8; ++ks) {
      if (ks + 2 < 8) {
#pragma unroll
        for (int ni = 0; ni < 4; ++ni)
          wf[(ks + 2) % 3][ni] = *(const bf16x8*)(w2b + ni * 4096 + (ks + 2) * 32);
      }
      bf16x8 hf[4];
#pragma unroll
      for (int mi = 0; mi < 4; ++mi) {
        const int row = mi * 16 + l15;
        const int ch = (ks * 4 + lq) ^ (row & 7);
        hf[mi] = *(const bf16x8*)&sh.m.Hl[row][ch * 8];
      }
#pragma unroll
      for (int mi = 0; mi < 4; ++mi)
#pragma unroll
        for (int ni = 0; ni < 4; ++ni)
          a2[mi][ni] = __builtin_amdgcn_mfma_f32_16x16x32_bf16(
              hf[mi], wf[ks % 3][ni], a2[mi][ni], 0, 0, 0);
    }

#pragma unroll
    for (int ni = 0; ni < 4; ++ni) {
      const int col = w * 64 + ni * 16 + l15;
      const float bb = b2v[ni];
#pragma unroll
      for (int mi = 0; mi < 4; ++mi) {
        const size_t grow0 = m0 + mi * 16 + 4 * lq;
        float z[4];
#pragma unroll
        for (int r = 0; r < 4; ++r) z[r] = a2[mi][ni][r] + bb;
        if (mlp != 2) {
#pragma unroll
          for (int r = 0; r < 4; ++r)
            dst[(grow0 + r) * 256 + col] = (u16)f2bfbits(z[r]);
        } else {  // v: transposed store vt[b][s=col][row]
          uint2 pv;
          pv.x = pk2(z[0], z[1]);
          pv.y = pk2(z[2], z[3]);
          const size_t bb2 = grow0 >> 10, lrow = grow0 & 1023;
          *(uint2*)(dst + ((size_t)bb2 * 256 + col) * 1024 + lrow) = pv;
        }
      }
    }
  }
}

// ---------------- fused attn + FC + ReLU + BN (v9) ----------
// 8 waves / 512 threads, 128 q-rows/block, KB=64, grid 256 (1 block/CU).
// Main loop = round-16 verbatim. Epilogue: normalize -> Osw (A-frag order)
// -> in-kernel FC GEMM (M=16/wave, N=256, K=256) + bias/ReLU/BN -> f32 out.
__global__ __launch_bounds__(512, 2)
void attn_mfma(const u16* __restrict__ Qa, const u16* __restrict__ Ka,
               const u16* __restrict__ Va,
               const u16* __restrict__ Qb, const u16* __restrict__ Kb,
               const u16* __restrict__ Vb,
               const u16* __restrict__ D1t, const float* __restrict__ D2,
               const u16* __restrict__ WtFC,  // Wt8 + 6*65536: [2][256][256]
               const float* __restrict__ fc1b, const float* __restrict__ fc2b,
               float* __restrict__ out1, float* __restrict__ out2,
               const float* __restrict__ bn_g, const float* __restrict__ bn_b,
               const float* __restrict__ bn_m, const float* __restrict__ bn_v)
{
  __shared__ union U {
    struct {
      u16 Ks[2][64][256];   // 65536 B, chunk-swizzle ch^(row&7)
      u16 Vts[2][256][64];  // 65536 B, chunk-swizzle ch^(row&7)
      u16 Pl[128][72];      // 18432 B P bf16 (wave-private 16-row slabs)
    } s;                    // 149504 B -> 1 block/CU
    u16 Osw[8][16][264];    // 67584 B epilogue transpose (per-wave)
  } u;

  const int orig = blockIdx.x;
  const int lid = (orig & 7) * 32 + (orig >> 3);  // bijective, 256 % 8 == 0
  const int dir = lid >> 7;
  const int b = (lid >> 3) & 15;
  const int i0 = (lid & 7) * 128;

  const u16* __restrict__ Q = dir ? Qb : Qa;
  const u16* __restrict__ K = dir ? Kb : Ka;
  const u16* __restrict__ Vt = dir ? Vb : Va;

  const int tid = threadIdx.x;
  const int lane = tid & 63;
  const int w = tid >> 6;  // 0..7
  const int l15 = lane & 15, lq = lane >> 4;
  const size_t sbase = (size_t)b * (1024 * 256);
  const size_t vtbase = (size_t)b * (256 * 1024);
  const size_t dbase = (size_t)b * (1024 * 1024);

  // Q fragments: lane covers q-row i0 + w*16 + l15, all 256 d
  bf16x8 q[8];
  {
    const u16* Qp = Q + sbase + (size_t)(i0 + w * 16 + l15) * 256 + lq * 8;
#pragma unroll
    for (int ks = 0; ks < 8; ++ks) q[ks] = *(const bf16x8*)(Qp + ks * 32);
  }

  const int cb0 = w * 4;
  auto stage_K = [&](int bi, int j0) {
#pragma unroll
    for (int i = 0; i < 4; ++i) {
      const int cb = cb0 + i;
      const int krow = cb * 2 + (lane >> 5);
      const int kch = (lane & 31) ^ (krow & 7);
      const u16* gs = K + sbase + (size_t)(j0 + krow) * 256 + kch * 8;
      __builtin_amdgcn_global_load_lds(
          (const __attribute__((address_space(1))) unsigned int*)gs,
          (__attribute__((address_space(3))) unsigned int*)&u.s.Ks[bi][cb * 2][0],
          16, 0, 0);
    }
  };
  auto stage_V = [&](int bi, int j0) {
#pragma unroll
    for (int i = 0; i < 4; ++i) {
      const int cb = cb0 + i;
      const int vrow = cb * 8 + (lane >> 3);
      const int vch = lane & 7;
      const u16* gs = Vt + vtbase + (size_t)vrow * 1024 + j0 + ((vch ^ (vrow & 7)) * 8);
      __builtin_amdgcn_global_load_lds(
          (const __attribute__((address_space(1))) unsigned int*)gs,
          (__attribute__((address_space(3))) unsigned int*)&u.s.Vts[bi][cb * 8][0],
          16, 0, 0);
    }
  };

  float mrow[4], lsum[4];
  f32x4 o[16];
#pragma unroll
  for (int r = 0; r < 4; ++r) { mrow[r] = -1e30f; lsum[r] = 0.f; }
#pragma unroll
  for (int nt = 0; nt < 16; ++nt) o[nt] = (f32x4)0.0f;

  stage_K(0, 0);
  stage_V(0, 0);  // prologue: K(0)+V(0) in flight (8 VMEM/wave)

  for (int t = 0; t < 16; ++t) {
    const int bi = t & 1;
    const int j0 = t * 64;

    // bias loads for tile t
    u16 bregu[16];
    float bregf[16];
    if (dir == 0) {
#pragma unroll
      for (int nt = 0; nt < 4; ++nt)
#pragma unroll
        for (int r = 0; r < 4; ++r)
          bregu[nt * 4 + r] =
              D1t[dbase + (size_t)(i0 + w * 16 + 4 * lq + r) * 1024 + j0 + l15 + 16 * nt];
    } else {
#pragma unroll
      for (int nt = 0; nt < 4; ++nt)
#pragma unroll
        for (int r = 0; r < 4; ++r)
          bregf[nt * 4 + r] =
              D2[dbase + (size_t)(i0 + w * 16 + 4 * lq + r) * 1024 + j0 + l15 + 16 * nt];
    }

    // prefetch tile t+1 (both K and V)
    if (t + 1 < 16) {
      stage_V(bi ^ 1, j0 + 64);
      stage_K(bi ^ 1, j0 + 64);
      asm volatile("s_waitcnt vmcnt(24)" ::: "memory");  // retire KV(t)
    } else {
      asm volatile("s_waitcnt vmcnt(16)" ::: "memory");  // retire KV(t)
    }
    __builtin_amdgcn_s_barrier();
    __builtin_amdgcn_sched_barrier(0);

    // QK^T: S[16 q-rows][64 keys] per wave
    f32x4 sa[4];
#pragma unroll
    for (int nt = 0; nt < 4; ++nt) sa[nt] = (f32x4)0.0f;
    __builtin_amdgcn_s_setprio(1);
#pragma unroll
    for (int ks = 0; ks < 8; ++ks)
#pragma unroll
      for (int nt = 0; nt < 4; ++nt) {
        const int row = nt * 16 + l15;
        const int cc = (ks * 4 + lq) ^ (row & 7);
        bf16x8 kb = *(const bf16x8*)&u.s.Ks[bi][row][cc * 8];
        sa[nt] = __builtin_amdgcn_mfma_f32_16x16x32_bf16(q[ks], kb, sa[nt], 0, 0, 0);
      }
    __builtin_amdgcn_s_setprio(0);

    // defer-max online softmax (THR=8); rows = w*16 + 4*lq + r
    float s[4][4];  // [r][nt]
    bool need = false;
#pragma unroll
    for (int r = 0; r < 4; ++r)
#pragma unroll
      for (int nt = 0; nt < 4; ++nt) {
        const float bb = (dir == 0) ? bf2f(bregu[nt * 4 + r]) : bregf[nt * 4 + r];
        s[r][nt] = sa[nt][r] * bb * 0.00390625f;
        need = need || (s[r][nt] > mrow[r] + 8.f);
      }
    if (__any(need)) {  // slow path: true max, rescale o and lsum
#pragma unroll
      for (int r = 0; r < 4; ++r) {
        float mx = fmaxf(fmaxf(s[r][0], s[r][1]), fmaxf(s[r][2], s[r][3]));
        mx = fmaxf(mx, __shfl_xor(mx, 1, 16));
        mx = fmaxf(mx, __shfl_xor(mx, 2, 16));
        mx = fmaxf(mx, __shfl_xor(mx, 4, 16));
        mx = fmaxf(mx, __shfl_xor(mx, 8, 16));
        const float mn = fmaxf(mrow[r], mx);
        const float sc = __expf(mrow[r] - mn);
        mrow[r] = mn;
        lsum[r] *= sc;
#pragma unroll
        for (int nt = 0; nt < 16; ++nt) o[nt][r] *= sc;
      }
    }
#pragma unroll
    for (int r = 0; r < 4; ++r) {
      const int qrow = w * 16 + 4 * lq + r;
#pragma unroll
      for (int nt = 0; nt < 4; ++nt) {
        const float p = __expf(s[r][nt] - mrow[r]);
        lsum[r] += p;
        u.s.Pl[qrow][nt * 16 + l15] = (u16)f2bfbits(p);
      }
    }
    asm volatile("s_waitcnt lgkmcnt(0)" ::: "memory");  // own Pl writes retired
    __builtin_amdgcn_sched_barrier(0);
    const bf16x8 pa0 = *(const bf16x8*)&u.s.Pl[w * 16 + l15][lq * 8];
    const bf16x8 pa1 = *(const bf16x8*)&u.s.Pl[w * 16 + l15][32 + lq * 8];

    // PV: O[16 q-rows][256 s], contraction over 64 keys (2 k-slots)
    __builtin_amdgcn_s_setprio(1);
#pragma unroll
    for (int nt = 0; nt < 16; ++nt) {
      const int row = nt * 16 + l15;
      const int cc0 = (0 * 4 + lq) ^ (row & 7);
      const int cc1 = (1 * 4 + lq) ^ (row & 7);
      bf16x8 vb0 = *(const bf16x8*)&u.s.Vts[bi][row][cc0 * 8];
      bf16x8 vb1 = *(const bf16x8*)&u.s.Vts[bi][row][cc1 * 8];
      o[nt] = __builtin_amdgcn_mfma_f32_16x16x32_bf16(pa0, vb0, o[nt], 0, 0, 0);
      o[nt] = __builtin_amdgcn_mfma_f32_16x16x32_bf16(pa1, vb1, o[nt], 0, 0, 0);
    }
    __builtin_amdgcn_s_setprio(0);

    asm volatile("s_waitcnt lgkmcnt(0)" ::: "memory");
    __builtin_amdgcn_s_barrier();  // tail: all DS reads of buf[bi] done before overwrite
  }

  // ---- epilogue part 1: reduce l, normalize, ap rows -> Osw (A-frag order) ----
  float inv[4];
#pragma unroll
  for (int r = 0; r < 4; ++r) {
    float rs = lsum[r];
    rs += __shfl_xor(rs, 1, 16);
    rs += __shfl_xor(rs, 2, 16);
    rs += __shfl_xor(rs, 4, 16);
    rs += __shfl_xor(rs, 8, 16);
    inv[r] = 1.0f / rs;
  }
  __builtin_amdgcn_s_barrier();  // all waves done with s-union before Osw overwrite
#pragma unroll
  for (int nt = 0; nt < 16; ++nt) {
#pragma unroll
    for (int r = 0; r < 4; ++r)
      u.Osw[w][4 * lq + r][nt * 16 + l15] = (u16)f2bfbits(o[nt][r] * inv[r]);
  }
  asm volatile("s_waitcnt lgkmcnt(0)" ::: "memory");  // wave-private slab ready
  __builtin_amdgcn_sched_barrier(0);

  // ---- epilogue part 2: fused FC + ReLU + BN ----
  // A-frags: Osw[w][l15][ks*32 + lq*8] (row=l15, k contiguous). Hoist all 8.
  bf16x8 afv[8];
#pragma unroll
  for (int ks = 0; ks < 8; ++ks)
    afv[ks] = *(const bf16x8*)&u.Osw[w][l15][ks * 32 + lq * 8];

  const u16* __restrict__ Wt = WtFC + (size_t)dir * 65536;  // [n][k] bf16
  const float* __restrict__ fcb = dir ? fc2b : fc1b;
  float* __restrict__ Cout = dir ? out2 : out1;
  const u16* __restrict__ wfb = Wt + (size_t)l15 * 256 + lq * 8;

#pragma unroll
  for (int nc = 0; nc < 4; ++nc) {
    f32x4 acc[4];
#pragma unroll
    for (int ni = 0; ni < 4; ++ni) acc[ni] = (f32x4)0.0f;
    bf16x8 wf[4], wn[4];
#pragma unroll
    for (int ni = 0; ni < 4; ++ni)
      wf[ni] = *(const bf16x8*)(wfb + (size_t)(nc * 64 + ni * 16) * 256);
#pragma unroll
    for (int ks = 0; ks < 8; ++ks) {
      if (ks < 7) {
#pragma unroll
        for (int ni = 0; ni < 4; ++ni)
          wn[ni] = *(const bf16x8*)(wfb + (size_t)(nc * 64 + ni * 16) * 256 + (ks + 1) * 32);
      }
#pragma unroll
      for (int ni = 0; ni < 4; ++ni)
        acc[ni] = __builtin_amdgcn_mfma_f32_16x16x32_bf16(afv[ks], wf[ni], acc[ni], 0, 0, 0);
#pragma unroll
      for (int ni = 0; ni < 4; ++ni) wf[ni] = wn[ni];
    }
#pragma unroll
    for (int ni = 0; ni < 4; ++ni) {
      const int col = nc * 64 + ni * 16 + l15;
      const float bi = fcb[col];
      const float g = bn_g[col];
      const float be = bn_b[col];
      const float mu = bn_m[col];
      const float iv = rsqrtf(bn_v[col] + 1e-3f);
      const size_t grow0 = sbase / 256 * 256;  // dummy to keep indices clear
      (void)grow0;
      const size_t row0 = (size_t)b * 1024 + i0 + w * 16 + 4 * lq;
#pragma unroll
      for (int r = 0; r < 4; ++r) {
        float z = acc[ni][r] + bi;
        float zz = fmaxf(z, 0.f);
        Cout[(row0 + r) * 256 + col] = (zz - mu) * iv * g + be;
      }
    }
  }
}

// ---------------- launch ----------------
extern "C" void kernel_launch(void* const* d_in, const int* in_sizes, int n_in,
                              void* d_out, int out_size, void* d_ws, size_t ws_size,
                              hipStream_t stream)
{
  (void)in_sizes; (void)n_in; (void)out_size; (void)ws_size;

  const float* seq1  = (const float*)d_in[0];
  const float* seq2  = (const float*)d_in[1];
  const float* disto = (const float*)d_in[2];
  const float* kW1 = (const float*)d_in[3];
  const float* kb1 = (const float*)d_in[4];
  const float* kW2 = (const float*)d_in[5];
  const float* kb2 = (const float*)d_in[6];
  const float* qW1 = (const float*)d_in[7];
  const float* qb1 = (const float*)d_in[8];
  const float* qW2 = (const float*)d_in[9];
  const float* qb2 = (const float*)d_in[10];
  const float* vW1 = (const float*)d_in[11];
  const float* vb1 = (const float*)d_in[12];
  const float* vW2 = (const float*)d_in[13];
  const float* vb2 = (const float*)d_in[14];
  const float* fc1W = (const float*)d_in[15];
  const float* fc1b = (const float*)d_in[16];
  const float* fc2W = (const float*)d_in[17];
  const float* fc2b = (const float*)d_in[18];
  const float* bn_g = (const float*)d_in[19];
  const float* bn_b = (const float*)d_in[20];
  const float* bn_m = (const float*)d_in[21];
  const float* bn_v = (const float*)d_in[22];

  char* ws = (char*)d_ws;
  const size_t MB = 1024 * 1024;
  u16* Wt8 = (u16*)(ws);                  // 1MB: 8 x 128KB
  u16* k1  = (u16*)(ws + 1 * MB);         // 8MB bf16 [16,1024,256] each
  u16* q1  = (u16*)(ws + 9 * MB);
  u16* k2  = (u16*)(ws + 17 * MB);
  u16* q2  = (u16*)(ws + 25 * MB);
  u16* v1t = (u16*)(ws + 33 * MB);        // [16,256,1024]
  u16* v2t = (u16*)(ws + 41 * MB);
  u16* D1t = (u16*)(ws + 65 * MB);        // 32MB bf16 [16,1024(m),1024(l)]

  pack_wt<<<dim3(64, 8), 256, 0, stream>>>(kW1, kW2, qW1, qW2, vW1, vW2, fc1W, fc2W, Wt8);

  // mlp3 (blocks 0..511) + disto transpose (blocks 512..4607), one launch
  mlp3_plus<<<dim3(4608), dim3(256), 0, stream>>>(
      seq1, seq2, Wt8, kb1, kb2, qb1, qb2, vb1, vb2,
      k1, q1, v1t, k2, q2, v2t, disto, D1t);

  // fused attention + FC + ReLU + BN, both directions, one 256-block launch
  float* out1 = (float*)d_out;
  float* out2 = (float*)d_out + 4194304;
  attn_mfma<<<dim3(256), dim3(512), 0, stream>>>(
      k2, q1, v1t,             // dir0: queries over L2, bias = D1t bf16
      k1, q2, v2t,             // dir1: queries over L1, bias = disto f32
      D1t, disto,
      Wt8 + 6ull * 65536, fc1b, fc2b, out1, out2,
      bn_g, bn_b, bn_m, bn_v);
}

// Round 18
// 161.247 us; speedup vs baseline: 1.0907x; 1.0907x over previous
//
#include <hip/hip_runtime.h>
#include <hip/hip_bf16.h>

// chem_transformer2D — round 18: REVERT to round-16 (best measured, 161.4us).
// Round-17's FC-fusion-into-attn-epilogue regressed (+32us on attn vs -13us
// saved): a 1-block/CU serial epilogue GEMM with per-block weight re-reads
// loses to the standalone well-tiled gemm_bn2 dispatch. Final composition:
//   pack_wt -> mlp3_plus (mlp3 || disto-transpose) -> attn (8-wave, KB=64,
//   counted vmcnt, defer-max) -> gemm_bn2 (both outputs, one launch).

typedef __attribute__((ext_vector_type(8))) short bf16x8;
typedef __attribute__((ext_vector_type(4))) float f32x4;
typedef unsigned short u16;

__device__ __forceinline__ unsigned int f2bfbits(float f) {
  union { float f; unsigned int i; } v; v.f = f;
  return (v.i + 0x7fffu + ((v.i >> 16) & 1u)) >> 16;  // RNE, finite inputs
}
__device__ __forceinline__ unsigned int pk2(float a, float b) {
  return f2bfbits(a) | (f2bfbits(b) << 16);
}
__device__ __forceinline__ float bf2f(u16 x) {
  union { unsigned int i; float f; } v;
  v.i = (unsigned int)x << 16;
  return v.f;
}

// ---------------- weight pack: W[256][256] f32 -> Wt[256][256] bf16 (Wt[n][k]=W[k][n]) ----
__global__ void pack_wt(const float* __restrict__ w0, const float* __restrict__ w1,
                        const float* __restrict__ w2, const float* __restrict__ w3,
                        const float* __restrict__ w4, const float* __restrict__ w5,
                        const float* __restrict__ w6, const float* __restrict__ w7,
                        u16* __restrict__ out) {
  const float* wsel[8] = {w0, w1, w2, w3, w4, w5, w6, w7};
  const float* W = wsel[blockIdx.y];
  u16* o = out + (size_t)blockIdx.y * 65536;
  int i0 = blockIdx.x * 1024 + threadIdx.x * 4;  // grid.x=64, block=256
  int n = i0 >> 8, k = i0 & 255;
  float a = W[(k + 0) * 256 + n];
  float b = W[(k + 1) * 256 + n];
  float c = W[(k + 2) * 256 + n];
  float d = W[(k + 3) * 256 + n];
  uint2 pv;
  pv.x = pk2(a, b);
  pv.y = pk2(c, d);
  *(uint2*)(o + i0) = pv;
}

// ---------------- merged: 3-MLP stack (blocks 0..511) + disto transpose (512..4607) ----
__global__ __launch_bounds__(256, 2)
void mlp3_plus(const float* __restrict__ seqA, const float* __restrict__ seqB,
               const u16* __restrict__ Wt8,
               const float* __restrict__ kb1, const float* __restrict__ kb2,
               const float* __restrict__ qb1, const float* __restrict__ qb2,
               const float* __restrict__ vb1, const float* __restrict__ vb2,
               u16* __restrict__ kA, u16* __restrict__ qA, u16* __restrict__ vA,
               u16* __restrict__ kB, u16* __restrict__ qB, u16* __restrict__ vB,
               const float* __restrict__ D, u16* __restrict__ Dt)
{
  __shared__ union {
    struct {
      u16 As[64][256];  // 32KB, chunk-swizzle ch^(row&7)
      u16 Hl[64][256];  // 32KB, same swizzle
    } m;
    u16 T[64][72];      // disto-transpose tile (+8 pad)
  } sh;

  const int tid = threadIdx.x;

  if (blockIdx.x >= 512) {
    // pack_disto path: Dt[b][m][l] = bf16(D[b][l][m])
    const int pb = blockIdx.x - 512;          // 0..4095
    const int m0 = (pb & 15) * 64;
    const int l0 = ((pb >> 4) & 15) * 64;
    const int b = pb >> 8;
    const float* src = D + (size_t)b * (1024 * 1024);
    u16* dst = Dt + (size_t)b * (1024 * 1024);
    const int r = tid >> 2, c0 = (tid & 3) * 16;
    float4 f[4];
#pragma unroll
    for (int q = 0; q < 4; ++q)
      f[q] = *(const float4*)(src + (size_t)(l0 + r) * 1024 + m0 + c0 + q * 4);
    uint4 p0, p1;
    p0.x = pk2(f[0].x, f[0].y); p0.y = pk2(f[0].z, f[0].w);
    p0.z = pk2(f[1].x, f[1].y); p0.w = pk2(f[1].z, f[1].w);
    p1.x = pk2(f[2].x, f[2].y); p1.y = pk2(f[2].z, f[2].w);
    p1.z = pk2(f[3].x, f[3].y); p1.w = pk2(f[3].z, f[3].w);
    *(uint4*)&sh.T[r][c0] = p0;
    *(uint4*)&sh.T[r][c0 + 8] = p1;
    __syncthreads();
    u16 vals[16];
#pragma unroll
    for (int k = 0; k < 16; ++k) vals[k] = sh.T[c0 + k][r];
    *(uint4*)(dst + (size_t)(m0 + r) * 1024 + l0 + c0) = *(uint4*)&vals[0];
    *(uint4*)(dst + (size_t)(m0 + r) * 1024 + l0 + c0 + 8) = *(uint4*)&vals[8];
    return;
  }

  // mlp3 path (depth-2 weight pipeline)
  const int lane = tid & 63;
  const int w = tid >> 6;
  const int l15 = lane & 15, lq = lane >> 4;
  const int seqsel = blockIdx.x >> 8;
  const size_t m0 = (size_t)(blockIdx.x & 255) * 64;
  const float* __restrict__ seq = seqsel ? seqB : seqA;

  {
    const int row = tid >> 2, cg = tid & 3;
    const float* src = seq + (m0 + row) * 256 + cg * 64;
#pragma unroll
    for (int cc = 0; cc < 8; ++cc) {
      float4 f0 = *(const float4*)(src + cc * 8);
      float4 f1 = *(const float4*)(src + cc * 8 + 4);
      uint4 pk;
      pk.x = pk2(f0.x, f0.y);
      pk.y = pk2(f0.z, f0.w);
      pk.z = pk2(f1.x, f1.y);
      pk.w = pk2(f1.z, f1.w);
      const int ch = (cg * 8 + cc) ^ (row & 7);
      *(uint4*)&sh.m.As[row][ch * 8] = pk;
    }
  }
  __syncthreads();

  for (int mlp = 0; mlp < 3; ++mlp) {
    const u16* __restrict__ W1 = Wt8 + (size_t)(mlp * 2) * 65536;
    const u16* __restrict__ W2 = W1 + 65536;
    const float* __restrict__ b1 = (mlp == 0) ? kb1 : (mlp == 1) ? qb1 : vb1;
    const float* __restrict__ b2 = (mlp == 0) ? kb2 : (mlp == 1) ? qb2 : vb2;
    u16* __restrict__ dst =
        (mlp == 0) ? (seqsel ? kB : kA) : (mlp == 1) ? (seqsel ? qB : qA) : (seqsel ? vB : vA);

    const u16* __restrict__ w1b = W1 + (size_t)(w * 64 + l15) * 256 + lq * 8;
    const u16* __restrict__ w2b = W2 + (size_t)(w * 64 + l15) * 256 + lq * 8;

    bf16x8 wf[3][4];
#pragma unroll
    for (int ni = 0; ni < 4; ++ni) wf[0][ni] = *(const bf16x8*)(w1b + ni * 4096);
#pragma unroll
    for (int ni = 0; ni < 4; ++ni) wf[1][ni] = *(const bf16x8*)(w1b + ni * 4096 + 32);

    float b1v[4][4];
#pragma unroll
    for (int ni = 0; ni < 4; ++ni)
#pragma unroll
      for (int r = 0; r < 4; ++r) b1v[ni][r] = b1[w * 64 + ni * 16 + 4 * lq + r];
    float b2v[4];
#pragma unroll
    for (int ni = 0; ni < 4; ++ni) b2v[ni] = b2[w * 64 + ni * 16 + l15];

    f32x4 a1[4][4];
#pragma unroll
    for (int ni = 0; ni < 4; ++ni)
#pragma unroll
      for (int mj = 0; mj < 4; ++mj) a1[ni][mj] = (f32x4)0.0f;
#pragma unroll
    for (int ks = 0; ks < 8; ++ks) {
      if (ks + 2 < 8) {
#pragma unroll
        for (int ni = 0; ni < 4; ++ni)
          wf[(ks + 2) % 3][ni] = *(const bf16x8*)(w1b + ni * 4096 + (ks + 2) * 32);
      }
      bf16x8 af[4];
#pragma unroll
      for (int mj = 0; mj < 4; ++mj) {
        const int row = mj * 16 + l15;
        const int ch = (ks * 4 + lq) ^ (row & 7);
        af[mj] = *(const bf16x8*)&sh.m.As[row][ch * 8];
      }
#pragma unroll
      for (int ni = 0; ni < 4; ++ni)
#pragma unroll
        for (int mj = 0; mj < 4; ++mj)
          a1[ni][mj] = __builtin_amdgcn_mfma_f32_16x16x32_bf16(
              wf[ks % 3][ni], af[mj], a1[ni][mj], 0, 0, 0);
    }

    __syncthreads();

#pragma unroll
    for (int ni = 0; ni < 4; ++ni) wf[0][ni] = *(const bf16x8*)(w2b + ni * 4096);
#pragma unroll
    for (int ni = 0; ni < 4; ++ni) wf[1][ni] = *(const bf16x8*)(w2b + ni * 4096 + 32);

#pragma unroll
    for (int ni = 0; ni < 4; ++ni) {
      const int chl = w * 8 + ni * 2 + (lq >> 1);
#pragma unroll
      for (int mj = 0; mj < 4; ++mj) {
        const int m = mj * 16 + l15;
        float h0 = fmaxf(a1[ni][mj][0] + b1v[ni][0], 0.f);
        float h1 = fmaxf(a1[ni][mj][1] + b1v[ni][1], 0.f);
        float h2 = fmaxf(a1[ni][mj][2] + b1v[ni][2], 0.f);
        float h3 = fmaxf(a1[ni][mj][3] + b1v[ni][3], 0.f);
        uint2 pv;
        pv.x = pk2(h0, h1);
        pv.y = pk2(h2, h3);
        const int ch = chl ^ (m & 7);
        *(uint2*)&sh.m.Hl[m][ch * 8 + (lq & 1) * 4] = pv;
      }
    }
    __syncthreads();

    f32x4 a2[4][4];
#pragma unroll
    for (int mi = 0; mi < 4; ++mi)
#pragma unroll
      for (int ni = 0; ni < 4; ++ni) a2[mi][ni] = (f32x4)0.0f;
#pragma unroll
    for (int ks = 0; ks < 8; ++ks) {
      if (ks + 2 < 8) {
#pragma unroll
        for (int ni = 0; ni < 4; ++ni)
          wf[(ks + 2) % 3][ni] = *(const bf16x8*)(w2b + ni * 4096 + (ks + 2) * 32);
      }
      bf16x8 hf[4];
#pragma unroll
      for (int mi = 0; mi < 4; ++mi) {
        const int row = mi * 16 + l15;
        const int ch = (ks * 4 + lq) ^ (row & 7);
        hf[mi] = *(const bf16x8*)&sh.m.Hl[row][ch * 8];
      }
#pragma unroll
      for (int mi = 0; mi < 4; ++mi)
#pragma unroll
        for (int ni = 0; ni < 4; ++ni)
          a2[mi][ni] = __builtin_amdgcn_mfma_f32_16x16x32_bf16(
              hf[mi], wf[ks % 3][ni], a2[mi][ni], 0, 0, 0);
    }

#pragma unroll
    for (int ni = 0; ni < 4; ++ni) {
      const int col = w * 64 + ni * 16 + l15;
      const float bb = b2v[ni];
#pragma unroll
      for (int mi = 0; mi < 4; ++mi) {
        const size_t grow0 = m0 + mi * 16 + 4 * lq;
        float z[4];
#pragma unroll
        for (int r = 0; r < 4; ++r) z[r] = a2[mi][ni][r] + bb;
        if (mlp != 2) {
#pragma unroll
          for (int r = 0; r < 4; ++r)
            dst[(grow0 + r) * 256 + col] = (u16)f2bfbits(z[r]);
        } else {  // v: transposed store vt[b][s=col][row]
          uint2 pv;
          pv.x = pk2(z[0], z[1]);
          pv.y = pk2(z[2], z[3]);
          const size_t bb2 = grow0 >> 10, lrow = grow0 & 1023;
          *(uint2*)(dst + ((size_t)bb2 * 256 + col) * 1024 + lrow) = pv;
        }
      }
    }
  }
}

// ---------------- merged BN GEMM pair: out_z = bn(relu(ap_z @ W_z + b_z)) ----------
__global__ __launch_bounds__(256, 2)
void gemm_bn2(const u16* __restrict__ ap1, const u16* __restrict__ ap2,
              const u16* __restrict__ Wt8,
              const float* __restrict__ fc1b, const float* __restrict__ fc2b,
              float* __restrict__ out1, float* __restrict__ out2,
              const float* __restrict__ bn_g, const float* __restrict__ bn_b,
              const float* __restrict__ bn_m, const float* __restrict__ bn_v)
{
  __shared__ u16 As[128][64];
  __shared__ u16 Ws[64][64];
  const int tid = threadIdx.x;
  const int lane = tid & 63;
  const int w = tid >> 6;
  const int wr = w >> 1, wc = w & 1;
  const int l15 = lane & 15, lq = lane >> 4;
  const size_t bm = (size_t)blockIdx.x * 128;
  const int bn = blockIdx.y * 64;
  const int which = blockIdx.z;

  const u16* __restrict__ A0 = which ? ap2 : ap1;
  const u16* __restrict__ Wt = Wt8 + (size_t)(6 + which) * 65536;
  const float* __restrict__ bias = which ? fc2b : fc1b;
  float* __restrict__ Cout = which ? out2 : out1;

  const int sar = tid >> 1, sah = tid & 1;
  const int swr = tid >> 2, swc = tid & 3;

  f32x4 acc[4][2];
#pragma unroll
  for (int mi = 0; mi < 4; ++mi)
#pragma unroll
    for (int ni = 0; ni < 2; ++ni) acc[mi][ni] = (f32x4)0.0f;

  for (int k0 = 0; k0 < 256; k0 += 64) {
    __syncthreads();
    {
      const u16* A = A0 + (bm + sar) * 256 + k0 + sah * 32;
#pragma unroll
      for (int c = 0; c < 4; ++c) {
        uint4 v = *(const uint4*)(A + c * 8);
        int cc = (sah * 4 + c) ^ (sar & 7);
        *(uint4*)&As[sar][cc * 8] = v;
      }
    }
    {
      const u16* Wp = Wt + (size_t)(bn + swr) * 256 + k0 + swc * 16;
#pragma unroll
      for (int c = 0; c < 2; ++c) {
        uint4 v = *(const uint4*)(Wp + c * 8);
        int cc = (swc * 2 + c) ^ (swr & 7);
        *(uint4*)&Ws[swr][cc * 8] = v;
      }
    }
    __syncthreads();
#pragma unroll
    for (int ks = 0; ks < 2; ++ks) {
      bf16x8 af[4], wf[2];
#pragma unroll
      for (int mi = 0; mi < 4; ++mi) {
        int row = wr * 64 + mi * 16 + l15;
        int cc = (ks * 4 + lq) ^ (row & 7);
        af[mi] = *(const bf16x8*)&As[row][cc * 8];
      }
#pragma unroll
      for (int ni = 0; ni < 2; ++ni) {
        int row = wc * 32 + ni * 16 + l15;
        int cc = (ks * 4 + lq) ^ (row & 7);
        wf[ni] = *(const bf16x8*)&Ws[row][cc * 8];
      }
#pragma unroll
      for (int mi = 0; mi < 4; ++mi)
#pragma unroll
        for (int ni = 0; ni < 2; ++ni)
          acc[mi][ni] = __builtin_amdgcn_mfma_f32_16x16x32_bf16(
              af[mi], wf[ni], acc[mi][ni], 0, 0, 0);
    }
  }

#pragma unroll
  for (int ni = 0; ni < 2; ++ni) {
    const int col = bn + wc * 32 + ni * 16 + l15;
    const float bi = bias[col];
    const float g = bn_g[col];
    const float be = bn_b[col];
    const float mu = bn_m[col];
    const float iv = rsqrtf(bn_v[col] + 1e-3f);
#pragma unroll
    for (int mi = 0; mi < 4; ++mi) {
      const size_t grow0 = bm + wr * 64 + mi * 16 + 4 * lq;
#pragma unroll
      for (int r = 0; r < 4; ++r) {
        float z = acc[mi][ni][r] + bi;
        float zz = fmaxf(z, 0.f);
        Cout[(grow0 + r) * 256 + col] = (zz - mu) * iv * g + be;
      }
    }
  }
}

// ---------------- fused dual-direction MFMA flash attention (v8: 8-wave, KB=64) ----------
// 512 threads, 128 q-rows/block, 64-key tiles, grid 256 (1 block/CU, 146KB LDS).
// K+V both double-buffered, prefetched at tile top; counted vmcnt(24); 2
// barriers/tile, 16 tiles. Defer-max softmax; D1t bf16 / disto f32 bias.
__global__ __launch_bounds__(512, 2)
void attn_mfma(const u16* __restrict__ Qa, const u16* __restrict__ Ka,
               const u16* __restrict__ Va, u16* __restrict__ OutA,
               const u16* __restrict__ Qb, const u16* __restrict__ Kb,
               const u16* __restrict__ Vb, u16* __restrict__ OutB,
               const u16* __restrict__ D1t, const float* __restrict__ D2)
{
  __shared__ union U {
    struct {
      u16 Ks[2][64][256];   // 65536 B, chunk-swizzle ch^(row&7)
      u16 Vts[2][256][64];  // 65536 B, chunk-swizzle ch^(row&7)
      u16 Pl[128][72];      // 18432 B P bf16 (wave-private 16-row slabs)
    } s;                    // 149504 B -> 1 block/CU
    u16 Osw[8][16][264];    // 67584 B epilogue transpose (per-wave)
  } u;

  const int orig = blockIdx.x;
  const int lid = (orig & 7) * 32 + (orig >> 3);  // bijective, 256 % 8 == 0
  const int dir = lid >> 7;
  const int b = (lid >> 3) & 15;
  const int i0 = (lid & 7) * 128;

  const u16* __restrict__ Q = dir ? Qb : Qa;
  const u16* __restrict__ K = dir ? Kb : Ka;
  const u16* __restrict__ Vt = dir ? Vb : Va;
  u16* __restrict__ Out = dir ? OutB : OutA;

  const int tid = threadIdx.x;
  const int lane = tid & 63;
  const int w = tid >> 6;  // 0..7
  const int l15 = lane & 15, lq = lane >> 4;
  const size_t sbase = (size_t)b * (1024 * 256);
  const size_t vtbase = (size_t)b * (256 * 1024);
  const size_t dbase = (size_t)b * (1024 * 1024);

  // Q fragments: lane covers q-row i0 + w*16 + l15, all 256 d
  bf16x8 q[8];
  {
    const u16* Qp = Q + sbase + (size_t)(i0 + w * 16 + l15) * 256 + lq * 8;
#pragma unroll
    for (int ks = 0; ks < 8; ++ks) q[ks] = *(const bf16x8*)(Qp + ks * 32);
  }

  // staging: per wave 4 K-issues + 4 V-issues of 1KB each, pre-swizzled src
  const int cb0 = w * 4;  // 0..28
  auto stage_K = [&](int bi, int j0) {
#pragma unroll
    for (int i = 0; i < 4; ++i) {
      const int cb = cb0 + i;                   // 0..31, 2 K-rows each
      const int krow = cb * 2 + (lane >> 5);
      const int kch = (lane & 31) ^ (krow & 7);
      const u16* gs = K + sbase + (size_t)(j0 + krow) * 256 + kch * 8;
      __builtin_amdgcn_global_load_lds(
          (const __attribute__((address_space(1))) unsigned int*)gs,
          (__attribute__((address_space(3))) unsigned int*)&u.s.Ks[bi][cb * 2][0],
          16, 0, 0);
    }
  };
  auto stage_V = [&](int bi, int j0) {
#pragma unroll
    for (int i = 0; i < 4; ++i) {
      const int cb = cb0 + i;                   // 0..31, 8 V-rows each
      const int vrow = cb * 8 + (lane >> 3);
      const int vch = lane & 7;
      const u16* gs = Vt + vtbase + (size_t)vrow * 1024 + j0 + ((vch ^ (vrow & 7)) * 8);
      __builtin_amdgcn_global_load_lds(
          (const __attribute__((address_space(1))) unsigned int*)gs,
          (__attribute__((address_space(3))) unsigned int*)&u.s.Vts[bi][cb * 8][0],
          16, 0, 0);
    }
  };

  float mrow[4], lsum[4];
  f32x4 o[16];
#pragma unroll
  for (int r = 0; r < 4; ++r) { mrow[r] = -1e30f; lsum[r] = 0.f; }
#pragma unroll
  for (int nt = 0; nt < 16; ++nt) o[nt] = (f32x4)0.0f;

  stage_K(0, 0);
  stage_V(0, 0);  // prologue: K(0)+V(0) in flight (8 VMEM/wave)

  for (int t = 0; t < 16; ++t) {
    const int bi = t & 1;
    const int j0 = t * 64;

    // bias loads for tile t: rows i0+w*16+4lq+r, keys j0 + nt*16 + l15 (nt=0..3)
    u16 bregu[16];
    float bregf[16];
    if (dir == 0) {
#pragma unroll
      for (int nt = 0; nt < 4; ++nt)
#pragma unroll
        for (int r = 0; r < 4; ++r)
          bregu[nt * 4 + r] =
              D1t[dbase + (size_t)(i0 + w * 16 + 4 * lq + r) * 1024 + j0 + l15 + 16 * nt];
    } else {
#pragma unroll
      for (int nt = 0; nt < 4; ++nt)
#pragma unroll
        for (int r = 0; r < 4; ++r)
          bregf[nt * 4 + r] =
              D2[dbase + (size_t)(i0 + w * 16 + 4 * lq + r) * 1024 + j0 + l15 + 16 * nt];
    }

    // prefetch tile t+1 (both K and V)
    if (t + 1 < 16) {
      stage_V(bi ^ 1, j0 + 64);
      stage_K(bi ^ 1, j0 + 64);
      // outstanding: KV(t)8 + bias16 + KV(t+1)8 = 32 -> retire KV(t)
      asm volatile("s_waitcnt vmcnt(24)" ::: "memory");
    } else {
      // outstanding: KV(t)8 + bias16 = 24 -> retire KV(t)
      asm volatile("s_waitcnt vmcnt(16)" ::: "memory");
    }
    __builtin_amdgcn_s_barrier();  // all waves' K(t)+V(t) visible
    __builtin_amdgcn_sched_barrier(0);

    // QK^T: S[16 q-rows][64 keys] per wave
    f32x4 sa[4];
#pragma unroll
    for (int nt = 0; nt < 4; ++nt) sa[nt] = (f32x4)0.0f;
    __builtin_amdgcn_s_setprio(1);
#pragma unroll
    for (int ks = 0; ks < 8; ++ks)
#pragma unroll
      for (int nt = 0; nt < 4; ++nt) {
        const int row = nt * 16 + l15;
        const int cc = (ks * 4 + lq) ^ (row & 7);
        bf16x8 kb = *(const bf16x8*)&u.s.Ks[bi][row][cc * 8];
        sa[nt] = __builtin_amdgcn_mfma_f32_16x16x32_bf16(q[ks], kb, sa[nt], 0, 0, 0);
      }
    __builtin_amdgcn_s_setprio(0);

    // defer-max online softmax (THR=8); rows = w*16 + 4*lq + r
    float s[4][4];  // [r][nt]
    bool need = false;
#pragma unroll
    for (int r = 0; r < 4; ++r)
#pragma unroll
      for (int nt = 0; nt < 4; ++nt) {
        const float bb = (dir == 0) ? bf2f(bregu[nt * 4 + r]) : bregf[nt * 4 + r];
        s[r][nt] = sa[nt][r] * bb * 0.00390625f;
        need = need || (s[r][nt] > mrow[r] + 8.f);
      }
    if (__any(need)) {  // slow path: true max, rescale o and lsum
#pragma unroll
      for (int r = 0; r < 4; ++r) {
        float mx = fmaxf(fmaxf(s[r][0], s[r][1]), fmaxf(s[r][2], s[r][3]));
        mx = fmaxf(mx, __shfl_xor(mx, 1, 16));
        mx = fmaxf(mx, __shfl_xor(mx, 2, 16));
        mx = fmaxf(mx, __shfl_xor(mx, 4, 16));
        mx = fmaxf(mx, __shfl_xor(mx, 8, 16));
        const float mn = fmaxf(mrow[r], mx);
        const float sc = __expf(mrow[r] - mn);
        mrow[r] = mn;
        lsum[r] *= sc;
#pragma unroll
        for (int nt = 0; nt < 16; ++nt) o[nt][r] *= sc;
      }
    }
#pragma unroll
    for (int r = 0; r < 4; ++r) {
      const int qrow = w * 16 + 4 * lq + r;
#pragma unroll
      for (int nt = 0; nt < 4; ++nt) {
        const float p = __expf(s[r][nt] - mrow[r]);
        lsum[r] += p;
        u.s.Pl[qrow][nt * 16 + l15] = (u16)f2bfbits(p);
      }
    }
    asm volatile("s_waitcnt lgkmcnt(0)" ::: "memory");  // own Pl writes retired
    __builtin_amdgcn_sched_barrier(0);
    const bf16x8 pa0 = *(const bf16x8*)&u.s.Pl[w * 16 + l15][lq * 8];
    const bf16x8 pa1 = *(const bf16x8*)&u.s.Pl[w * 16 + l15][32 + lq * 8];

    // PV: O[16 q-rows][256 s], contraction over 64 keys (2 k-slots)
    __builtin_amdgcn_s_setprio(1);
#pragma unroll
    for (int nt = 0; nt < 16; ++nt) {
      const int row = nt * 16 + l15;
      const int cc0 = (0 * 4 + lq) ^ (row & 7);
      const int cc1 = (1 * 4 + lq) ^ (row & 7);
      bf16x8 vb0 = *(const bf16x8*)&u.s.Vts[bi][row][cc0 * 8];
      bf16x8 vb1 = *(const bf16x8*)&u.s.Vts[bi][row][cc1 * 8];
      o[nt] = __builtin_amdgcn_mfma_f32_16x16x32_bf16(pa0, vb0, o[nt], 0, 0, 0);
      o[nt] = __builtin_amdgcn_mfma_f32_16x16x32_bf16(pa1, vb1, o[nt], 0, 0, 0);
    }
    __builtin_amdgcn_s_setprio(0);

    asm volatile("s_waitcnt lgkmcnt(0)" ::: "memory");
    __builtin_amdgcn_s_barrier();  // tail: all DS reads of buf[bi] done before overwrite
  }

  // epilogue: reduce l once, normalize, transpose via LDS, coalesced store
  float inv[4];
#pragma unroll
  for (int r = 0; r < 4; ++r) {
    float rs = lsum[r];
    rs += __shfl_xor(rs, 1, 16);
    rs += __shfl_xor(rs, 2, 16);
    rs += __shfl_xor(rs, 4, 16);
    rs += __shfl_xor(rs, 8, 16);
    inv[r] = 1.0f / rs;
  }
  __builtin_amdgcn_s_barrier();  // all waves done with s-union before Osw overwrite
#pragma unroll
  for (int nt = 0; nt < 16; ++nt) {
#pragma unroll
    for (int r = 0; r < 4; ++r)
      u.Osw[w][4 * lq + r][nt * 16 + l15] = (u16)f2bfbits(o[nt][r] * inv[r]);
  }
  asm volatile("s_waitcnt lgkmcnt(0)" ::: "memory");
  __builtin_amdgcn_sched_barrier(0);
  {
    const int orow = lane >> 2, och = (lane & 3) * 64;
    const u16* src = &u.Osw[w][orow][och];
    u16* dst = Out + sbase + (size_t)(i0 + w * 16 + orow) * 256 + och;
#pragma unroll
    for (int c = 0; c < 8; ++c) *(uint4*)(dst + c * 8) = *(const uint4*)(src + c * 8);
  }
}

// ---------------- launch ----------------
extern "C" void kernel_launch(void* const* d_in, const int* in_sizes, int n_in,
                              void* d_out, int out_size, void* d_ws, size_t ws_size,
                              hipStream_t stream)
{
  (void)in_sizes; (void)n_in; (void)out_size; (void)ws_size;

  const float* seq1  = (const float*)d_in[0];
  const float* seq2  = (const float*)d_in[1];
  const float* disto = (const float*)d_in[2];
  const float* kW1 = (const float*)d_in[3];
  const float* kb1 = (const float*)d_in[4];
  const float* kW2 = (const float*)d_in[5];
  const float* kb2 = (const float*)d_in[6];
  const float* qW1 = (const float*)d_in[7];
  const float* qb1 = (const float*)d_in[8];
  const float* qW2 = (const float*)d_in[9];
  const float* qb2 = (const float*)d_in[10];
  const float* vW1 = (const float*)d_in[11];
  const float* vb1 = (const float*)d_in[12];
  const float* vW2 = (const float*)d_in[13];
  const float* vb2 = (const float*)d_in[14];
  const float* fc1W = (const float*)d_in[15];
  const float* fc1b = (const float*)d_in[16];
  const float* fc2W = (const float*)d_in[17];
  const float* fc2b = (const float*)d_in[18];
  const float* bn_g = (const float*)d_in[19];
  const float* bn_b = (const float*)d_in[20];
  const float* bn_m = (const float*)d_in[21];
  const float* bn_v = (const float*)d_in[22];

  char* ws = (char*)d_ws;
  const size_t MB = 1024 * 1024;
  u16* Wt8 = (u16*)(ws);                  // 1MB: 8 x 128KB
  u16* k1  = (u16*)(ws + 1 * MB);         // 8MB bf16 [16,1024,256] each
  u16* q1  = (u16*)(ws + 9 * MB);
  u16* k2  = (u16*)(ws + 17 * MB);
  u16* q2  = (u16*)(ws + 25 * MB);
  u16* v1t = (u16*)(ws + 33 * MB);        // [16,256,1024]
  u16* v2t = (u16*)(ws + 41 * MB);
  u16* ap1 = (u16*)(ws + 49 * MB);
  u16* ap2 = (u16*)(ws + 57 * MB);
  u16* D1t = (u16*)(ws + 65 * MB);        // 32MB bf16 [16,1024(m),1024(l)]

  pack_wt<<<dim3(64, 8), 256, 0, stream>>>(kW1, kW2, qW1, qW2, vW1, vW2, fc1W, fc2W, Wt8);

  // mlp3 (blocks 0..511) + disto transpose (blocks 512..4607), one launch
  mlp3_plus<<<dim3(4608), dim3(256), 0, stream>>>(
      seq1, seq2, Wt8, kb1, kb2, qb1, qb2, vb1, vb2,
      k1, q1, v1t, k2, q2, v2t, disto, D1t);

  // fused attention, both directions, one 256-block launch (8 waves/block)
  attn_mfma<<<dim3(256), dim3(512), 0, stream>>>(
      k2, q1, v1t, ap1,        // dir0: queries over L2, bias = D1t bf16
      k1, q2, v2t, ap2,        // dir1: queries over L1, bias = disto f32
      D1t, disto);

  // both FC+ReLU+BN GEMMs in one launch (z selects stream)
  float* out1 = (float*)d_out;
  float* out2 = (float*)d_out + 4194304;
  gemm_bn2<<<dim3(128, 4, 2), dim3(256), 0, stream>>>(
      ap1, ap2, Wt8, fc1b, fc2b, out1, out2, bn_g, bn_b, bn_m, bn_v);
}